// Round 1
// baseline (1524.200 us; speedup 1.0000x reference)
//
#include <hip/hip_runtime.h>

#define NN 650
#define NA 250
#define NO 400
#define NE 100000

typedef short bf16x8_t __attribute__((ext_vector_type(8)));
typedef float f32x4_t __attribute__((ext_vector_type(4)));

__device__ __forceinline__ unsigned short f2bf(float f) {
  union { float f; unsigned u; } x; x.f = f;
  unsigned r = x.u + 0x7fffu + ((x.u >> 16) & 1u);
  return (unsigned short)(r >> 16);
}
__device__ __forceinline__ float bf2f(unsigned short u) {
  union { unsigned u; float f; } x; x.u = ((unsigned)u) << 16; return x.f;
}

// ---------------- adjacency build ----------------
__global__ void k_scatter(const int* __restrict__ src, const int* __restrict__ dst,
                          float* __restrict__ C, float* __restrict__ deg) {
  int e = blockIdx.x * 256 + threadIdx.x;
  if (e < NE) {
    int s = src[e], d = dst[e];
    atomicAdd(&C[d * NN + s], 1.0f);
    atomicAdd(&deg[d], 1.0f);
  }
}

// Cn[i][j] = C[i][j] / max(deg[i],1), padded to 672 cols with zeros, bf16
__global__ void k_adj_norm(const float* __restrict__ C, const float* __restrict__ deg,
                           unsigned short* __restrict__ Cn) {
  int idx = blockIdx.x * 256 + threadIdx.x;
  if (idx >= NN * 672) return;
  int i = idx / 672, j = idx - i * 672;
  float v = (j < NN) ? C[i * NN + j] / fmaxf(deg[i], 1.0f) : 0.0f;
  Cn[idx] = f2bf(v);
}

// ---------------- f32 -> bf16 convert with K-pad ----------------
__global__ void k_cvt(const float* __restrict__ in, unsigned short* __restrict__ out,
                      int M, int Kin, int ldi, int off, int ldo) {
  int idx = blockIdx.x * 256 + threadIdx.x;
  if (idx >= M * ldo) return;
  int r = idx / ldo, c = idx - r * ldo;
  out[idx] = (c < Kin) ? f2bf(in[(size_t)r * ldi + off + c]) : (unsigned short)0;
}

// out[c][r] = in[r][c], rows padded to ldo with zeros (bf16 -> bf16)
__global__ void k_transpose_bf(const unsigned short* __restrict__ in, unsigned short* __restrict__ out,
                               int Min, int Kcols, int ldi, int ldo) {
  int idx = blockIdx.x * 256 + threadIdx.x;
  if (idx >= Kcols * ldo) return;
  int c = idx / ldo, r = idx - c * ldo;
  out[idx] = (r < Min) ? in[(size_t)r * ldi + c] : (unsigned short)0;
}

// ---------------- MFMA GEMM: C[m,n] = sum_k A[m,k]*B[n,k] ----------------
// A: (M x K) bf16 (lda == K, K % 32 == 0), B: (N x K) bf16 (ldb == K)
// AMODE==1: A generated on the fly: A[pair,k] = relu(Pa[pair/400][k] + Po[pair%400][k]), k<1200
// bias (len N, f32) and addb (M x ldc f32) optional (nullptr). OUT_BF: bf16 out else f32.
// Stores for n < Ncover; value 0 for N <= n < Ncover (zero-padding of out columns).
template<int AMODE, int OUT_BF, int RELU>
__launch_bounds__(256)
__global__ void k_gemm(const unsigned short* __restrict__ A,
                       const unsigned short* __restrict__ B,
                       const float* __restrict__ bias,
                       const float* __restrict__ addb,
                       void* __restrict__ Cout,
                       int M, int N, int K, int ldc, int Ncover,
                       const float* __restrict__ Pa, const float* __restrict__ Po) {
  __shared__ unsigned short As[64 * 32];
  __shared__ unsigned short Bs[64 * 32];
  const int tid = threadIdx.x;
  const int m0 = blockIdx.x * 64;
  const int n0 = blockIdx.y * 64;
  const int arow = tid >> 2;          // 0..63
  const int acol = (tid & 3) * 8;     // 0,8,16,24
  const int wave = tid >> 6, lane = tid & 63;
  const int lr = lane & 15, q = lane >> 4;

  f32x4_t acc[4];
#pragma unroll
  for (int t = 0; t < 4; ++t) { f32x4_t z = {0.f, 0.f, 0.f, 0.f}; acc[t] = z; }

  const float* pa = nullptr; const float* po = nullptr; int pok = 0;
  if (AMODE == 1) {
    int pair = m0 + arow;
    if (pair < M) { pok = 1; int a = pair / 400; int o = pair - a * 400; pa = Pa + a * 1200; po = Po + o * 1200; }
  }

  for (int k0 = 0; k0 < K; k0 += 32) {
    // ---- stage A tile (64 x 32) ----
    if (AMODE == 0) {
      uint4 av = {0u, 0u, 0u, 0u};
      if (m0 + arow < M) av = *(const uint4*)(A + (size_t)(m0 + arow) * K + k0 + acol);
      *(uint4*)(As + arow * 32 + acol) = av;
    } else {
      int kk = k0 + acol;
      unsigned short t8[8];
      if (pok && kk < 1200) {
        float4 x1 = *(const float4*)(pa + kk);
        float4 x2 = *(const float4*)(pa + kk + 4);
        float4 y1 = *(const float4*)(po + kk);
        float4 y2 = *(const float4*)(po + kk + 4);
        t8[0] = f2bf(fmaxf(x1.x + y1.x, 0.f)); t8[1] = f2bf(fmaxf(x1.y + y1.y, 0.f));
        t8[2] = f2bf(fmaxf(x1.z + y1.z, 0.f)); t8[3] = f2bf(fmaxf(x1.w + y1.w, 0.f));
        t8[4] = f2bf(fmaxf(x2.x + y2.x, 0.f)); t8[5] = f2bf(fmaxf(x2.y + y2.y, 0.f));
        t8[6] = f2bf(fmaxf(x2.z + y2.z, 0.f)); t8[7] = f2bf(fmaxf(x2.w + y2.w, 0.f));
      } else {
#pragma unroll
        for (int j = 0; j < 8; ++j) t8[j] = 0;
      }
#pragma unroll
      for (int j = 0; j < 8; ++j) As[arow * 32 + acol + j] = t8[j];
    }
    // ---- stage B tile (64 x 32) ----
    {
      uint4 bv = {0u, 0u, 0u, 0u};
      if (n0 + arow < N) bv = *(const uint4*)(B + (size_t)(n0 + arow) * K + k0 + acol);
      *(uint4*)(Bs + arow * 32 + acol) = bv;
    }
    __syncthreads();
    // ---- MFMA: wave w handles rows [w*16, w*16+16), all 64 cols ----
    bf16x8_t af = *(const bf16x8_t*)(As + (wave * 16 + lr) * 32 + q * 8);
#pragma unroll
    for (int t = 0; t < 4; ++t) {
      bf16x8_t bfv = *(const bf16x8_t*)(Bs + (t * 16 + lr) * 32 + q * 8);
      acc[t] = __builtin_amdgcn_mfma_f32_16x16x32_bf16(af, bfv, acc[t], 0, 0, 0);
    }
    __syncthreads();
  }

  // ---- epilogue: D row=(lane>>4)*4+reg, col=lane&15 ----
#pragma unroll
  for (int t = 0; t < 4; ++t) {
#pragma unroll
    for (int r = 0; r < 4; ++r) {
      int gm = m0 + wave * 16 + q * 4 + r;
      int gn = n0 + t * 16 + lr;
      if (gm < M && gn < Ncover) {
        float v = 0.f;
        if (gn < N) {
          v = acc[t][r];
          if (bias) v += bias[gn];
          if (addb) v += addb[(size_t)gm * ldc + gn];
          if (RELU) v = fmaxf(v, 0.f);
        }
        if (OUT_BF) ((unsigned short*)Cout)[(size_t)gm * ldc + gn] = f2bf(v);
        else        ((float*)Cout)[(size_t)gm * ldc + gn] = v;
      }
    }
  }
}

// ---------------- LayerNorm over D=800, out bf16 ----------------
template<int INF32>
__global__ void k_ln(const void* __restrict__ in, unsigned short* __restrict__ out,
                     const float* __restrict__ g, const float* __restrict__ b) {
  const int row = blockIdx.x, t = threadIdx.x;
  const float* inf = (const float*)in;
  const unsigned short* inb = (const unsigned short*)in;
  float v[4]; float s = 0.f, ss = 0.f; int j = 0;
  for (int idx = t; idx < 800; idx += 256, ++j) {
    float x = INF32 ? inf[(size_t)row * 800 + idx] : bf2f(inb[(size_t)row * 800 + idx]);
    v[j] = x; s += x; ss += x * x;
  }
#pragma unroll
  for (int off = 32; off > 0; off >>= 1) {
    s += __shfl_down(s, off);
    ss += __shfl_down(ss, off);
  }
  __shared__ float sh[8];
  int wave = t >> 6, lane = t & 63;
  if (lane == 0) { sh[wave] = s; sh[4 + wave] = ss; }
  __syncthreads();
  if (t == 0) {
    float S = sh[0] + sh[1] + sh[2] + sh[3];
    float SS = sh[4] + sh[5] + sh[6] + sh[7];
    float m = S * (1.0f / 800.0f);
    float var = SS * (1.0f / 800.0f) - m * m;
    sh[0] = m; sh[1] = rsqrtf(fmaxf(var, 0.f) + 1e-5f);
  }
  __syncthreads();
  float m = sh[0], inv = sh[1];
  j = 0;
  for (int idx = t; idx < 800; idx += 256, ++j) {
    float y = (v[j] - m) * inv * g[idx] + b[idx];
    out[(size_t)row * 800 + idx] = f2bf(y);
  }
}

// ---------------- host ----------------
extern "C" void kernel_launch(void* const* d_in, const int* in_sizes, int n_in,
                              void* d_out, int out_size, void* d_ws, size_t ws_size,
                              hipStream_t stream) {
  (void)in_sizes; (void)n_in; (void)out_size; (void)ws_size;
  const float* img  = (const float*)d_in[0];
  const float* nodes= (const float*)d_in[1];
  const int* esrc   = (const int*)d_in[2];
  const int* edst   = (const int*)d_in[3];
  const float* W1l  = (const float*)d_in[4];
  const float* b1   = (const float*)d_in[5];
  const float* W1r  = (const float*)d_in[6];
  const float* W2l  = (const float*)d_in[7];
  const float* b2   = (const float*)d_in[8];
  const float* W2r  = (const float*)d_in[9];
  const float* Wp1  = (const float*)d_in[10];
  const float* bp1  = (const float*)d_in[11];
  const float* Wp2  = (const float*)d_in[12];
  const float* bp2  = (const float*)d_in[13];
  const float* gp   = (const float*)d_in[14];
  const float* bpn  = (const float*)d_in[15];
  const float* Wi1  = (const float*)d_in[16];
  const float* bi1  = (const float*)d_in[17];
  const float* Wi2  = (const float*)d_in[18];
  const float* bi2  = (const float*)d_in[19];
  const float* Wi3  = (const float*)d_in[20];
  const float* bi3  = (const float*)d_in[21];
  const float* gi   = (const float*)d_in[22];
  const float* binp = (const float*)d_in[23];

  char* wsp = (char*)d_ws;
  auto alloc = [&](size_t bytes) -> void* {
    void* p = (void*)wsp; wsp += (bytes + 255) & ~(size_t)255; return p;
  };
  float* adjC = (float*)alloc((size_t)NN * NN * 4);
  float* deg  = (float*)alloc(NN * 4);
  unsigned short* Cn     = (unsigned short*)alloc((size_t)NN * 672 * 2);
  unsigned short* nodesB = (unsigned short*)alloc((size_t)NN * 512 * 2);
  unsigned short* nodesT = (unsigned short*)alloc((size_t)512 * 672 * 2);
  unsigned short* agg1   = (unsigned short*)alloc((size_t)NN * 512 * 2);
  float* tmp1            = (float*)alloc((size_t)NN * 4096 * 4);
  unsigned short* hB     = (unsigned short*)alloc((size_t)NN * 4096 * 2);
  unsigned short* hT     = (unsigned short*)alloc((size_t)4096 * 672 * 2);
  unsigned short* agg2   = (unsigned short*)alloc((size_t)NN * 4096 * 2);
  float* tmp2            = (float*)alloc((size_t)NN * 512 * 4);
  unsigned short* onB    = (unsigned short*)alloc((size_t)NN * 512 * 2);
  unsigned short* W1lB   = (unsigned short*)alloc((size_t)4096 * 512 * 2);
  unsigned short* W1rB   = (unsigned short*)alloc((size_t)4096 * 512 * 2);
  unsigned short* W2lB   = (unsigned short*)alloc((size_t)512 * 4096 * 2);
  unsigned short* W2rB   = (unsigned short*)alloc((size_t)512 * 4096 * 2);
  unsigned short* Wp1LB  = (unsigned short*)alloc((size_t)1200 * 512 * 2);
  unsigned short* Wp1RB  = (unsigned short*)alloc((size_t)1200 * 512 * 2);
  unsigned short* Wp2B   = (unsigned short*)alloc((size_t)800 * 1216 * 2);
  unsigned short* Wi1B   = (unsigned short*)alloc((size_t)768 * 2048 * 2);
  unsigned short* Wi2B   = (unsigned short*)alloc((size_t)1000 * 768 * 2);
  unsigned short* Wi3B   = (unsigned short*)alloc((size_t)800 * 1024 * 2);
  unsigned short* imgB   = (unsigned short*)alloc((size_t)256 * 2048 * 2);
  float* PaB             = (float*)alloc((size_t)250 * 1200 * 4);
  float* PoB             = (float*)alloc((size_t)400 * 1200 * 4);
  unsigned short* pB     = (unsigned short*)alloc((size_t)100000 * 800 * 2);
  unsigned short* i1B    = (unsigned short*)alloc((size_t)256 * 768 * 2);
  unsigned short* i2B    = (unsigned short*)alloc((size_t)256 * 1024 * 2);
  float* i3F             = (float*)alloc((size_t)256 * 800 * 4);
  unsigned short* iB     = (unsigned short*)alloc((size_t)256 * 800 * 2);

  hipMemsetAsync(adjC, 0, (size_t)NN * NN * 4, stream);
  hipMemsetAsync(deg, 0, NN * 4, stream);

  k_scatter<<<dim3((NE + 255) / 256), 256, 0, stream>>>(esrc, edst, adjC, deg);
  k_adj_norm<<<dim3((NN * 672 + 255) / 256), 256, 0, stream>>>(adjC, deg, Cn);

  auto cv = [&](const float* in, unsigned short* out, int M, int Kin, int ldi, int off, int ldo) {
    k_cvt<<<dim3((M * ldo + 255) / 256), 256, 0, stream>>>(in, out, M, Kin, ldi, off, ldo);
  };
  cv(nodes, nodesB, NN, 512, 512, 0, 512);
  cv(W1l, W1lB, 4096, 512, 512, 0, 512);
  cv(W1r, W1rB, 4096, 512, 512, 0, 512);
  cv(W2l, W2lB, 512, 4096, 4096, 0, 4096);
  cv(W2r, W2rB, 512, 4096, 4096, 0, 4096);
  cv(Wp1, Wp1LB, 1200, 512, 1024, 0, 512);
  cv(Wp1, Wp1RB, 1200, 512, 1024, 512, 512);
  cv(Wp2, Wp2B, 800, 1200, 1200, 0, 1216);
  cv(Wi1, Wi1B, 768, 2048, 2048, 0, 2048);
  cv(Wi2, Wi2B, 1000, 768, 768, 0, 768);
  cv(Wi3, Wi3B, 800, 1000, 1000, 0, 1024);
  cv(img, imgB, 256, 2048, 2048, 0, 2048);

  k_transpose_bf<<<dim3((512 * 672 + 255) / 256), 256, 0, stream>>>(nodesB, nodesT, NN, 512, 512, 672);

#define GDIM(M, NC) dim3(((M) + 63) / 64, ((NC) + 63) / 64)
  // agg1 = Cn @ nodes (bf16 out)
  k_gemm<0, 1, 0><<<GDIM(650, 512), 256, 0, stream>>>(Cn, nodesT, nullptr, nullptr, agg1, 650, 512, 672, 512, 512, nullptr, nullptr);
  // tmp1 = agg1 @ W1l.T + b1 (f32)
  k_gemm<0, 0, 0><<<GDIM(650, 4096), 256, 0, stream>>>(agg1, W1lB, b1, nullptr, tmp1, 650, 4096, 512, 4096, 4096, nullptr, nullptr);
  // h = relu(nodes @ W1r.T + tmp1) (bf16)
  k_gemm<0, 1, 1><<<GDIM(650, 4096), 256, 0, stream>>>(nodesB, W1rB, nullptr, tmp1, hB, 650, 4096, 512, 4096, 4096, nullptr, nullptr);
  k_transpose_bf<<<dim3((4096 * 672 + 255) / 256), 256, 0, stream>>>(hB, hT, NN, 4096, 4096, 672);
  // agg2 = Cn @ h (bf16)
  k_gemm<0, 1, 0><<<GDIM(650, 4096), 256, 0, stream>>>(Cn, hT, nullptr, nullptr, agg2, 650, 4096, 672, 4096, 4096, nullptr, nullptr);
  // tmp2 = agg2 @ W2l.T + b2 (f32)
  k_gemm<0, 0, 0><<<GDIM(650, 512), 256, 0, stream>>>(agg2, W2lB, b2, nullptr, tmp2, 650, 512, 4096, 512, 512, nullptr, nullptr);
  // out_nodes = h @ W2r.T + tmp2 (bf16)
  k_gemm<0, 1, 0><<<GDIM(650, 512), 256, 0, stream>>>(hB, W2rB, nullptr, tmp2, onB, 650, 512, 4096, 512, 512, nullptr, nullptr);
  // Pa = attr @ Wp1L.T + bp1 ; Po = obj @ Wp1R.T (f32)
  k_gemm<0, 0, 0><<<GDIM(250, 1200), 256, 0, stream>>>(onB, Wp1LB, bp1, nullptr, PaB, 250, 1200, 512, 1200, 1200, nullptr, nullptr);
  k_gemm<0, 0, 0><<<GDIM(400, 1200), 256, 0, stream>>>(onB + 250 * 512, Wp1RB, nullptr, nullptr, PoB, 400, 1200, 512, 1200, 1200, nullptr, nullptr);
  // q = relu(Pa+Po) @ Wp2.T + bp2 (bf16, A generated on the fly)
  k_gemm<1, 1, 0><<<GDIM(100000, 800), 256, 0, stream>>>(Wp2B, Wp2B, bp2, nullptr, pB, 100000, 800, 1216, 800, 800, PaB, PoB);
  // p = LN(q) * gp + bpn (in-place bf16)
  k_ln<0><<<dim3(100000), 256, 0, stream>>>(pB, pB, gp, bpn);
  // image branch
  k_gemm<0, 1, 1><<<GDIM(256, 768), 256, 0, stream>>>(imgB, Wi1B, bi1, nullptr, i1B, 256, 768, 2048, 768, 768, nullptr, nullptr);
  k_gemm<0, 1, 1><<<GDIM(256, 1024), 256, 0, stream>>>(i1B, Wi2B, bi2, nullptr, i2B, 256, 1000, 768, 1024, 1024, nullptr, nullptr);
  k_gemm<0, 0, 0><<<GDIM(256, 800), 256, 0, stream>>>(i2B, Wi3B, bi3, nullptr, i3F, 256, 800, 1024, 800, 800, nullptr, nullptr);
  k_ln<1><<<dim3(256), 256, 0, stream>>>(i3F, iB, gi, binp);
  // out = i @ p.T (f32, 256 x 100000)
  k_gemm<0, 0, 0><<<GDIM(256, 100000), 256, 0, stream>>>(iB, pB, nullptr, nullptr, (float*)d_out, 256, 100000, 800, 100000, 100000, nullptr, nullptr);
#undef GDIM
}

// Round 3
// 1514.574 us; speedup vs baseline: 1.0064x; 1.0064x over previous
//
#include <hip/hip_runtime.h>

#define NN 650
#define NE 100000

typedef short bf16x8_t __attribute__((ext_vector_type(8)));
typedef float f32x4_t __attribute__((ext_vector_type(4)));

__device__ __forceinline__ unsigned short f2bf(float f) {
  union { float f; unsigned u; } x; x.f = f;
  unsigned r = x.u + 0x7fffu + ((x.u >> 16) & 1u);
  return (unsigned short)(r >> 16);
}
__device__ __forceinline__ float bf2f(unsigned short u) {
  union { unsigned u; float f; } x; x.u = ((unsigned)u) << 16; return x.f;
}

typedef const __attribute__((address_space(1))) unsigned int* gptr_t;
typedef __attribute__((address_space(3))) unsigned int* lptr_t;
__device__ __forceinline__ void gl_lds16(const unsigned short* g, unsigned short* l) {
  __builtin_amdgcn_global_load_lds((gptr_t)g, (lptr_t)l, 16, 0, 0);
}

// ---------------- adjacency build ----------------
__global__ void k_scatter(const int* __restrict__ src, const int* __restrict__ dst,
                          float* __restrict__ C, float* __restrict__ deg) {
  int e = blockIdx.x * 256 + threadIdx.x;
  if (e < NE) {
    int s = src[e], d = dst[e];
    atomicAdd(&C[d * NN + s], 1.0f);
    atomicAdd(&deg[d], 1.0f);
  }
}

// Cn[i][j] = C[i][j]/max(deg[i],1); 768 rows x 672 cols, zero-padded, bf16
__global__ void k_adj_norm(const float* __restrict__ C, const float* __restrict__ deg,
                           unsigned short* __restrict__ Cn) {
  int idx = blockIdx.x * 256 + threadIdx.x;
  if (idx >= 768 * 672) return;
  int i = idx / 672, j = idx - i * 672;
  float v = (i < NN && j < NN) ? C[i * NN + j] / fmaxf(deg[i], 1.0f) : 0.0f;
  Cn[idx] = f2bf(v);
}

// ---------------- f32 -> bf16 convert, row+col zero-pad ----------------
__global__ void k_cvt(const float* __restrict__ in, unsigned short* __restrict__ out,
                      int Mvalid, int Mpad, int Kin, int ldi, int off, int ldo) {
  int idx = blockIdx.x * 256 + threadIdx.x;
  if (idx >= Mpad * ldo) return;
  int r = idx / ldo, c = idx - r * ldo;
  out[idx] = (r < Mvalid && c < Kin) ? f2bf(in[(size_t)r * ldi + off + c]) : (unsigned short)0;
}

// out[c][r] = in[r][c]; out has Kcols rows x ldo cols, r>=Min zero-padded
__global__ void k_transpose_bf(const unsigned short* __restrict__ in, unsigned short* __restrict__ out,
                               int Min, int Kcols, int ldi, int ldo) {
  int idx = blockIdx.x * 256 + threadIdx.x;
  if (idx >= Kcols * ldo) return;
  int c = idx / ldo, r = idx - c * ldo;
  out[idx] = (r < Min) ? in[(size_t)r * ldi + c] : (unsigned short)0;
}

// ---- P chunk: P[local][k] = relu(Pa[(r0+local)/400][k] + Po[(r0+local)%400][k]) ----
// P: rows x 1216 bf16; global pair index p = r0 + local; p >= 100000 -> zero row.
__global__ void k_pgen(const float* __restrict__ Pa, const float* __restrict__ Po,
                       unsigned short* __restrict__ P, int r0, int rows) {
  int g = blockIdx.x * 256 + threadIdx.x;        // group of 8 elements
  if (g >= rows * 152) return;
  int lp = g / 152, k = (g - lp * 152) * 8;
  int p = r0 + lp;
  unsigned short t8[8];
  if (p < 100000) {
    int a = p / 400, o = p - a * 400;
    const float* pa = Pa + (size_t)a * 1216 + k;
    const float* po = Po + (size_t)o * 1216 + k;
    float4 x1 = *(const float4*)(pa);
    float4 x2 = *(const float4*)(pa + 4);
    float4 y1 = *(const float4*)(po);
    float4 y2 = *(const float4*)(po + 4);
    t8[0] = f2bf(fmaxf(x1.x + y1.x, 0.f)); t8[1] = f2bf(fmaxf(x1.y + y1.y, 0.f));
    t8[2] = f2bf(fmaxf(x1.z + y1.z, 0.f)); t8[3] = f2bf(fmaxf(x1.w + y1.w, 0.f));
    t8[4] = f2bf(fmaxf(x2.x + y2.x, 0.f)); t8[5] = f2bf(fmaxf(x2.y + y2.y, 0.f));
    t8[6] = f2bf(fmaxf(x2.z + y2.z, 0.f)); t8[7] = f2bf(fmaxf(x2.w + y2.w, 0.f));
  } else {
#pragma unroll
    for (int j = 0; j < 8; ++j) t8[j] = 0;
  }
  *(bf16x8_t*)(P + (size_t)lp * 1216 + k) = *(bf16x8_t*)t8;
}

// ---------------- m97-style MFMA GEMM: C[m,n] = sum_k A[m,k]*B[n,k] ----------------
// BM=BN=128, BK=32, 256 threads (4 waves, 2x2), global_load_lds staging.
// A rows and B rows MUST be padded to the grid coverage (no bounds checks in loop).
// Epilogue: v=0 outside (Mvalid,Nvalid); store only gn<Nstore.
#define BK 32
template<int OUT_BF, int RELU>
__launch_bounds__(256)
__global__ void k_gemm128(const unsigned short* __restrict__ A,
                          const unsigned short* __restrict__ B,
                          const float* __restrict__ bias,
                          const float* __restrict__ addb,
                          void* __restrict__ Cout,
                          int K, int ldc,
                          int Mvalid, int Nvalid, int Nstore, int swap) {
  __shared__ unsigned short As[128 * BK];
  __shared__ unsigned short Bs[128 * BK];
  const int tid = threadIdx.x;
  const int w = tid >> 6, lane = tid & 63;
  const int bm = swap ? blockIdx.y : blockIdx.x;
  const int bn = swap ? blockIdx.x : blockIdx.y;
  const int m0 = bm * 128, n0 = bn * 128;
  const int wm = w & 1, wn = w >> 1;
  const int lr = lane & 15, q = lane >> 4;

  // staging: wave w loads rows [w*32, w*32+32) of A and of B, 2 issues of 16 rows
  const int srow = w * 32 + (lane >> 2);
  const int scol = (lane & 3) * 8;
  const unsigned short* Ag = A + (size_t)(m0 + srow) * K + scol;
  const unsigned short* Bg = B + (size_t)(n0 + srow) * K + scol;
  unsigned short* Asl0 = As + (w * 32) * BK;
  unsigned short* Asl1 = As + (w * 32 + 16) * BK;
  unsigned short* Bsl0 = Bs + (w * 32) * BK;
  unsigned short* Bsl1 = Bs + (w * 32 + 16) * BK;

  f32x4_t acc[4][4];
#pragma unroll
  for (int r = 0; r < 4; ++r)
#pragma unroll
    for (int t = 0; t < 4; ++t) { f32x4_t z = {0.f, 0.f, 0.f, 0.f}; acc[r][t] = z; }

  for (int k0 = 0; k0 < K; k0 += BK) {
    __syncthreads();
    gl_lds16(Ag, Asl0);
    gl_lds16(Ag + 16 * (size_t)K, Asl1);
    gl_lds16(Bg, Bsl0);
    gl_lds16(Bg + 16 * (size_t)K, Bsl1);
    Ag += BK; Bg += BK;
    __syncthreads();
    bf16x8_t af[4], bfv[4];
#pragma unroll
    for (int r = 0; r < 4; ++r)
      af[r] = *(const bf16x8_t*)(As + (wm * 64 + r * 16 + lr) * BK + q * 8);
#pragma unroll
    for (int t = 0; t < 4; ++t)
      bfv[t] = *(const bf16x8_t*)(Bs + (wn * 64 + t * 16 + lr) * BK + q * 8);
#pragma unroll
    for (int r = 0; r < 4; ++r)
#pragma unroll
      for (int t = 0; t < 4; ++t)
        acc[r][t] = __builtin_amdgcn_mfma_f32_16x16x32_bf16(af[r], bfv[t], acc[r][t], 0, 0, 0);
  }

#pragma unroll
  for (int r = 0; r < 4; ++r) {
#pragma unroll
    for (int t = 0; t < 4; ++t) {
#pragma unroll
      for (int e = 0; e < 4; ++e) {
        int gm = m0 + wm * 64 + r * 16 + q * 4 + e;
        int gn = n0 + wn * 64 + t * 16 + lr;
        if (gn < Nstore) {
          float v = 0.f;
          if (gm < Mvalid && gn < Nvalid) {
            v = acc[r][t][e];
            if (bias) v += bias[gn];
            if (addb) v += addb[(size_t)gm * ldc + gn];
            if (RELU) v = fmaxf(v, 0.f);
          }
          if (OUT_BF) ((unsigned short*)Cout)[(size_t)gm * ldc + gn] = f2bf(v);
          else        ((float*)Cout)[(size_t)gm * ldc + gn] = v;
        }
      }
    }
  }
}

// ---------------- LayerNorm over D=800, out bf16 ----------------
template<int INF32>
__global__ void k_ln(const void* __restrict__ in, unsigned short* __restrict__ out,
                     const float* __restrict__ g, const float* __restrict__ b) {
  const int row = blockIdx.x, t = threadIdx.x;
  const float* inf = (const float*)in;
  const unsigned short* inb = (const unsigned short*)in;
  float v[4]; float s = 0.f, ss = 0.f; int j = 0;
  for (int idx = t; idx < 800; idx += 256, ++j) {
    float x = INF32 ? inf[(size_t)row * 800 + idx] : bf2f(inb[(size_t)row * 800 + idx]);
    v[j] = x; s += x; ss += x * x;
  }
#pragma unroll
  for (int off = 32; off > 0; off >>= 1) {
    s += __shfl_down(s, off);
    ss += __shfl_down(ss, off);
  }
  __shared__ float sh[8];
  int wave = t >> 6, lane = t & 63;
  if (lane == 0) { sh[wave] = s; sh[4 + wave] = ss; }
  __syncthreads();
  if (t == 0) {
    float S = sh[0] + sh[1] + sh[2] + sh[3];
    float SS = sh[4] + sh[5] + sh[6] + sh[7];
    float m = S * (1.0f / 800.0f);
    float var = SS * (1.0f / 800.0f) - m * m;
    sh[0] = m; sh[1] = rsqrtf(fmaxf(var, 0.f) + 1e-5f);
  }
  __syncthreads();
  float m = sh[0], inv = sh[1];
  j = 0;
  for (int idx = t; idx < 800; idx += 256, ++j) {
    float y = (v[j] - m) * inv * g[idx] + b[idx];
    out[(size_t)row * 800 + idx] = f2bf(y);
  }
}

// ---------------- host ----------------
extern "C" void kernel_launch(void* const* d_in, const int* in_sizes, int n_in,
                              void* d_out, int out_size, void* d_ws, size_t ws_size,
                              hipStream_t stream) {
  (void)in_sizes; (void)n_in; (void)out_size; (void)ws_size;
  const float* img  = (const float*)d_in[0];
  const float* nodes= (const float*)d_in[1];
  const int* esrc   = (const int*)d_in[2];
  const int* edst   = (const int*)d_in[3];
  const float* W1l  = (const float*)d_in[4];
  const float* b1   = (const float*)d_in[5];
  const float* W1r  = (const float*)d_in[6];
  const float* W2l  = (const float*)d_in[7];
  const float* b2   = (const float*)d_in[8];
  const float* W2r  = (const float*)d_in[9];
  const float* Wp1  = (const float*)d_in[10];
  const float* bp1  = (const float*)d_in[11];
  const float* Wp2  = (const float*)d_in[12];
  const float* bp2  = (const float*)d_in[13];
  const float* gp   = (const float*)d_in[14];
  const float* bpn  = (const float*)d_in[15];
  const float* Wi1  = (const float*)d_in[16];
  const float* bi1  = (const float*)d_in[17];
  const float* Wi2  = (const float*)d_in[18];
  const float* bi2  = (const float*)d_in[19];
  const float* Wi3  = (const float*)d_in[20];
  const float* bi3  = (const float*)d_in[21];
  const float* gi   = (const float*)d_in[22];
  const float* binp = (const float*)d_in[23];

  // ---- workspace layout: [persistent ~19MB][pB 160MB, node-stage scratch overlays it]
  char* wsp = (char*)d_ws;
  auto alloc = [&](size_t bytes) -> void* {
    void* p = (void*)wsp; wsp += (bytes + 255) & ~(size_t)255; return p;
  };
  // persistent (live across the pair stage)
  unsigned short* onB    = (unsigned short*)alloc((size_t)768 * 512 * 2);
  unsigned short* Wp1LB  = (unsigned short*)alloc((size_t)1280 * 512 * 2);
  unsigned short* Wp1RB  = (unsigned short*)alloc((size_t)1280 * 512 * 2);
  unsigned short* Wp2B   = (unsigned short*)alloc((size_t)896 * 1216 * 2);
  float* PaB             = (float*)alloc((size_t)256 * 1216 * 4);
  float* PoB             = (float*)alloc((size_t)512 * 1216 * 4);
  unsigned short* imgB   = (unsigned short*)alloc((size_t)256 * 2048 * 2);
  unsigned short* Wi1B   = (unsigned short*)alloc((size_t)768 * 2048 * 2);
  unsigned short* Wi2B   = (unsigned short*)alloc((size_t)1024 * 768 * 2);
  unsigned short* Wi3B   = (unsigned short*)alloc((size_t)896 * 1024 * 2);
  unsigned short* i1B    = (unsigned short*)alloc((size_t)256 * 768 * 2);
  unsigned short* i2B    = (unsigned short*)alloc((size_t)256 * 1024 * 2);
  float* i3F             = (float*)alloc((size_t)256 * 800 * 4);
  unsigned short* iB     = (unsigned short*)alloc((size_t)256 * 800 * 2);
  unsigned short* pB     = (unsigned short*)alloc((size_t)100096 * 800 * 2);

  // node-stage scratch overlays the pB region (dead before first pB write)
  char* swp = (char*)pB;
  auto salloc = [&](size_t bytes) -> void* {
    void* p = (void*)swp; swp += (bytes + 255) & ~(size_t)255; return p;
  };
  float* adjC            = (float*)salloc((size_t)NN * NN * 4);
  float* deg             = (float*)salloc(NN * 4);
  unsigned short* Cn     = (unsigned short*)salloc((size_t)768 * 672 * 2);
  unsigned short* nodesB = (unsigned short*)salloc((size_t)768 * 512 * 2);
  unsigned short* nodesT = (unsigned short*)salloc((size_t)512 * 672 * 2);
  unsigned short* agg1   = (unsigned short*)salloc((size_t)768 * 512 * 2);
  float* tmp1            = (float*)salloc((size_t)768 * 4096 * 4);
  unsigned short* hB     = (unsigned short*)salloc((size_t)768 * 4096 * 2);
  unsigned short* hT     = (unsigned short*)salloc((size_t)4096 * 672 * 2);
  unsigned short* agg2   = (unsigned short*)salloc((size_t)768 * 4096 * 2);
  float* tmp2            = (float*)salloc((size_t)768 * 512 * 4);
  unsigned short* W1lB   = (unsigned short*)salloc((size_t)4096 * 512 * 2);
  unsigned short* W1rB   = (unsigned short*)salloc((size_t)4096 * 512 * 2);
  unsigned short* W2lB   = (unsigned short*)salloc((size_t)512 * 4096 * 2);
  unsigned short* W2rB   = (unsigned short*)salloc((size_t)512 * 4096 * 2);

  // P chunk scratch lives in d_out (102.4 MB; scratch-legal until the final GEMM)
  unsigned short* Pch = (unsigned short*)d_out;  // 25088*1216*2 = 61.0 MB max

  hipMemsetAsync(adjC, 0, (size_t)NN * NN * 4, stream);
  hipMemsetAsync(deg, 0, NN * 4, stream);

  k_scatter<<<dim3((NE + 255) / 256), 256, 0, stream>>>(esrc, edst, adjC, deg);
  k_adj_norm<<<dim3((768 * 672 + 255) / 256), 256, 0, stream>>>(adjC, deg, Cn);

  auto cv = [&](const float* in, unsigned short* out, int Mvalid, int Mpad, int Kin, int ldi, int off, int ldo) {
    k_cvt<<<dim3((Mpad * ldo + 255) / 256), 256, 0, stream>>>(in, out, Mvalid, Mpad, Kin, ldi, off, ldo);
  };
  cv(nodes, nodesB, 650, 768, 512, 512, 0, 512);
  cv(W1l, W1lB, 4096, 4096, 512, 512, 0, 512);
  cv(W1r, W1rB, 4096, 4096, 512, 512, 0, 512);
  cv(W2l, W2lB, 512, 512, 4096, 4096, 0, 4096);
  cv(W2r, W2rB, 512, 512, 4096, 4096, 0, 4096);
  cv(Wp1, Wp1LB, 1200, 1280, 512, 1024, 0, 512);
  cv(Wp1, Wp1RB, 1200, 1280, 512, 1024, 512, 512);
  cv(Wp2, Wp2B, 800, 896, 1200, 1200, 0, 1216);
  cv(Wi1, Wi1B, 768, 768, 2048, 2048, 0, 2048);
  cv(Wi2, Wi2B, 1000, 1024, 768, 768, 0, 768);
  cv(Wi3, Wi3B, 800, 896, 1000, 1000, 0, 1024);
  cv(img, imgB, 256, 256, 2048, 2048, 0, 2048);

  k_transpose_bf<<<dim3((512 * 672 + 255) / 256), 256, 0, stream>>>(nodesB, nodesT, 650, 512, 512, 672);

  // ---- node stage (scratch region) ----
  k_gemm128<1, 0><<<dim3(6, 4), 256, 0, stream>>>(Cn, nodesT, nullptr, nullptr, agg1, 672, 512, 650, 512, 512, 0);
  k_gemm128<0, 0><<<dim3(6, 32), 256, 0, stream>>>(agg1, W1lB, b1, nullptr, tmp1, 512, 4096, 650, 4096, 4096, 0);
  k_gemm128<1, 1><<<dim3(6, 32), 256, 0, stream>>>(nodesB, W1rB, nullptr, tmp1, hB, 512, 4096, 650, 4096, 4096, 0);
  k_transpose_bf<<<dim3((4096 * 672 + 255) / 256), 256, 0, stream>>>(hB, hT, 650, 4096, 4096, 672);
  k_gemm128<1, 0><<<dim3(6, 32), 256, 0, stream>>>(Cn, hT, nullptr, nullptr, agg2, 672, 4096, 650, 4096, 4096, 0);
  k_gemm128<0, 0><<<dim3(6, 4), 256, 0, stream>>>(agg2, W2lB, b2, nullptr, tmp2, 4096, 512, 650, 512, 512, 0);
  k_gemm128<1, 0><<<dim3(6, 4), 256, 0, stream>>>(hB, W2rB, nullptr, tmp2, onB, 4096, 512, 650, 512, 512, 0);
  // Pa = attr @ Wp1L.T + bp1 ; Po = obj @ Wp1R.T (f32, ld 1216, cols 1200..1215 zero)
  k_gemm128<0, 0><<<dim3(2, 10), 256, 0, stream>>>(onB, Wp1LB, bp1, nullptr, PaB, 512, 1216, 250, 1200, 1216, 0);
  k_gemm128<0, 0><<<dim3(4, 10), 256, 0, stream>>>(onB + 250 * 512, Wp1RB, nullptr, nullptr, PoB, 512, 1216, 400, 1200, 1216, 0);

  // ---- image branch (persistent buffers only) ----
  k_gemm128<1, 1><<<dim3(2, 6), 256, 0, stream>>>(imgB, Wi1B, bi1, nullptr, i1B, 2048, 768, 256, 768, 768, 0);
  k_gemm128<1, 1><<<dim3(2, 8), 256, 0, stream>>>(i1B, Wi2B, bi2, nullptr, i2B, 768, 1024, 256, 1000, 1024, 0);
  k_gemm128<0, 0><<<dim3(2, 7), 256, 0, stream>>>(i2B, Wi3B, bi3, nullptr, i3F, 1024, 800, 256, 800, 800, 0);
  k_ln<1><<<dim3(256), 256, 0, stream>>>(i3F, iB, gi, binp);

  // ---- pair stage, chunked: P chunk in d_out, consumed immediately ----
  const int CB = 196;                       // m-blocks per chunk (25088 rows, 61 MB)
  for (int c = 0; c < 4; ++c) {
    int b0 = c * CB;
    int nb = (782 - b0) < CB ? (782 - b0) : CB;   // 196,196,196,194
    int r0 = b0 * 128;
    int rows = nb * 128;
    k_pgen<<<dim3((rows * 152 + 255) / 256), 256, 0, stream>>>(PaB, PoB, Pch, r0, rows);
    int mv = (100000 - r0) < rows ? (100000 - r0) : rows;
    k_gemm128<1, 0><<<dim3(7, nb), 256, 0, stream>>>(Pch, Wp2B, bp2, nullptr,
        pB + (size_t)r0 * 800, 1216, 800, mv, 800, 800, 1);
  }
  // p = LN(q) in-place
  k_ln<0><<<dim3(100000), 256, 0, stream>>>(pB, pB, gp, bpn);

  // ---- out = i @ p.T (f32, 256 x 100000) ----
  k_gemm128<0, 0><<<dim3(2, 782), 256, 0, stream>>>(iB, pB, nullptr, nullptr, (float*)d_out, 800, 100000, 256, 100000, 100000, 0);
}

// Round 4
// 1397.854 us; speedup vs baseline: 1.0904x; 1.0835x over previous
//
#include <hip/hip_runtime.h>

#define NN 650
#define NE 100000

typedef short bf16x8_t __attribute__((ext_vector_type(8)));
typedef short s16x4_t __attribute__((ext_vector_type(4)));
typedef float f32x4_t __attribute__((ext_vector_type(4)));

__device__ __forceinline__ unsigned short f2bf(float f) {
  union { float f; unsigned u; } x; x.f = f;
  unsigned r = x.u + 0x7fffu + ((x.u >> 16) & 1u);
  return (unsigned short)(r >> 16);
}
__device__ __forceinline__ float bf2f(unsigned short u) {
  union { unsigned u; float f; } x; x.u = ((unsigned)u) << 16; return x.f;
}

typedef const __attribute__((address_space(1))) unsigned int* gptr_t;
typedef __attribute__((address_space(3))) unsigned int* lptr_t;
__device__ __forceinline__ void gl_lds16(const unsigned short* g, unsigned short* l) {
  __builtin_amdgcn_global_load_lds((gptr_t)g, (lptr_t)l, 16, 0, 0);
}

// ---------------- adjacency build ----------------
__global__ void k_scatter(const int* __restrict__ src, const int* __restrict__ dst,
                          float* __restrict__ C, float* __restrict__ deg) {
  int e = blockIdx.x * 256 + threadIdx.x;
  if (e < NE) {
    int s = src[e], d = dst[e];
    atomicAdd(&C[d * NN + s], 1.0f);
    atomicAdd(&deg[d], 1.0f);
  }
}

// Cn[i][j] = C[i][j]/max(deg[i],1); 768 rows x 672 cols, zero-padded, bf16
__global__ void k_adj_norm(const float* __restrict__ C, const float* __restrict__ deg,
                           unsigned short* __restrict__ Cn) {
  int idx = blockIdx.x * 256 + threadIdx.x;
  if (idx >= 768 * 672) return;
  int i = idx / 672, j = idx - i * 672;
  float v = (i < NN && j < NN) ? C[i * NN + j] / fmaxf(deg[i], 1.0f) : 0.0f;
  Cn[idx] = f2bf(v);
}

// ---------------- fused f32->bf16 converts (12 jobs, 1 launch) ----------------
#define MAXJ 12
struct CvtDesc { const float* src; unsigned short* dst; int Mvalid, Kin, ldi, off, ldo, nElem, nblk; };
struct CvtPack { CvtDesc d[MAXJ]; };
__global__ void k_cvt_all(CvtPack P) {
  int b = blockIdx.x;
  int j = 0;
  while (b >= P.d[j].nblk) { b -= P.d[j].nblk; ++j; }
  const CvtDesc D = P.d[j];
  int idx = b * 256 + threadIdx.x;
  if (idx >= D.nElem) return;
  int r = idx / D.ldo, c = idx - r * D.ldo;
  D.dst[idx] = (r < D.Mvalid && c < D.Kin) ? f2bf(D.src[(size_t)r * D.ldi + D.off + c]) : (unsigned short)0;
}

// ---------------- LDS-tiled transpose: out[c][r] = in[r][c] ----------------
// grid (Kcols/64, ceil(ldo/64)); in must have >= round_up(ldo,64) rows allocated
// (rows beyond valid data must be zero). Kcols % 64 == 0, ldo % 4 == 0.
__global__ void k_ttr(const unsigned short* __restrict__ in, unsigned short* __restrict__ out,
                      int ldi, int ldo) {
  __shared__ unsigned short tile[64][65];
  const int c0 = blockIdx.x * 64, r0 = blockIdx.y * 64;
  const int t = threadIdx.x;
  const int rl = t >> 4, cl = (t & 15) * 4;
#pragma unroll
  for (int rr = 0; rr < 4; ++rr) {
    s16x4_t v = *(const s16x4_t*)(in + (size_t)(r0 + rl + rr * 16) * ldi + c0 + cl);
#pragma unroll
    for (int j = 0; j < 4; ++j) tile[rl + rr * 16][cl + j] = (unsigned short)v[j];
  }
  __syncthreads();
  if (r0 + cl < ldo) {
#pragma unroll
    for (int cc = 0; cc < 4; ++cc) {
      int crow = rl + cc * 16;
      unsigned short o[4] = { tile[cl + 0][crow], tile[cl + 1][crow],
                              tile[cl + 2][crow], tile[cl + 3][crow] };
      *(s16x4_t*)(out + (size_t)(c0 + crow) * ldo + r0 + cl) = *(s16x4_t*)o;
    }
  }
}

// ---- P chunk: P[local][k] = relu(Pa[(r0+local)/400][k] + Po[(r0+local)%400][k]) ----
__global__ void k_pgen(const float* __restrict__ Pa, const float* __restrict__ Po,
                       unsigned short* __restrict__ P, int r0, int rows) {
  int g = blockIdx.x * 256 + threadIdx.x;        // group of 8 elements
  if (g >= rows * 152) return;
  int lp = g / 152, k = (g - lp * 152) * 8;
  int p = r0 + lp;
  unsigned short t8[8];
  if (p < 100000) {
    int a = p / 400, o = p - a * 400;
    const float* pa = Pa + (size_t)a * 1216 + k;
    const float* po = Po + (size_t)o * 1216 + k;
    float4 x1 = *(const float4*)(pa);
    float4 x2 = *(const float4*)(pa + 4);
    float4 y1 = *(const float4*)(po);
    float4 y2 = *(const float4*)(po + 4);
    t8[0] = f2bf(fmaxf(x1.x + y1.x, 0.f)); t8[1] = f2bf(fmaxf(x1.y + y1.y, 0.f));
    t8[2] = f2bf(fmaxf(x1.z + y1.z, 0.f)); t8[3] = f2bf(fmaxf(x1.w + y1.w, 0.f));
    t8[4] = f2bf(fmaxf(x2.x + y2.x, 0.f)); t8[5] = f2bf(fmaxf(x2.y + y2.y, 0.f));
    t8[6] = f2bf(fmaxf(x2.z + y2.z, 0.f)); t8[7] = f2bf(fmaxf(x2.w + y2.w, 0.f));
  } else {
#pragma unroll
    for (int j = 0; j < 8; ++j) t8[j] = 0;
  }
  *(bf16x8_t*)(P + (size_t)lp * 1216 + k) = *(bf16x8_t*)t8;
}

// ---- per-row mean/rsqrt stats of q (rows x 800 bf16), vectorized, read-only ----
// block 256 = 2 rows (rows must be even); writes mA[row], ivA[row]
__global__ void k_qstats(const unsigned short* __restrict__ q,
                         float* __restrict__ mA, float* __restrict__ ivA, int r0) {
  const int half = threadIdx.x >> 7, t = threadIdx.x & 127;
  const int row = r0 + blockIdx.x * 2 + half;
  float s = 0.f, ss = 0.f;
  if (t < 100) {
    bf16x8_t v = *(const bf16x8_t*)(q + (size_t)row * 800 + t * 8);
#pragma unroll
    for (int j = 0; j < 8; ++j) { float f = bf2f((unsigned short)v[j]); s += f; ss += f * f; }
  }
#pragma unroll
  for (int off = 32; off > 0; off >>= 1) { s += __shfl_down(s, off); ss += __shfl_down(ss, off); }
  __shared__ float sh[8];
  int w = threadIdx.x >> 6, lane = threadIdx.x & 63;
  if (lane == 0) { sh[w] = s; sh[4 + w] = ss; }
  __syncthreads();
  if (t == 0) {
    int wb = half * 2;
    float S = sh[wb] + sh[wb + 1], SS = sh[4 + wb] + sh[4 + wb + 1];
    float m = S * (1.0f / 800.0f);
    float var = SS * (1.0f / 800.0f) - m * m;
    mA[row] = m;
    ivA[row] = rsqrtf(fmaxf(var, 0.f) + 1e-5f);
  }
}

// ---- iG = bf16(i * gp); c1 = sum(i*gp); c2 = sum(i*bpn). 256 rows, 128 thr/row ----
__global__ void k_prep_i(const unsigned short* __restrict__ iB,
                         const float* __restrict__ gp, const float* __restrict__ bpn,
                         unsigned short* __restrict__ iG,
                         float* __restrict__ c1, float* __restrict__ c2) {
  const int row = blockIdx.x, t = threadIdx.x;   // 128 threads
  float s1 = 0.f, s2 = 0.f;
  if (t < 100) {
    bf16x8_t v = *(const bf16x8_t*)(iB + (size_t)row * 800 + t * 8);
    unsigned short o[8];
#pragma unroll
    for (int j = 0; j < 8; ++j) {
      float f = bf2f((unsigned short)v[j]);
      float g = gp[t * 8 + j];
      s1 += f * g; s2 += f * bpn[t * 8 + j];
      o[j] = f2bf(f * g);
    }
    *(bf16x8_t*)(iG + (size_t)row * 800 + t * 8) = *(bf16x8_t*)o;
  }
#pragma unroll
  for (int off = 32; off > 0; off >>= 1) { s1 += __shfl_down(s1, off); s2 += __shfl_down(s2, off); }
  __shared__ float sh[4];
  int w = t >> 6, lane = t & 63;
  if (lane == 0) { sh[w] = s1; sh[2 + w] = s2; }
  __syncthreads();
  if (t == 0) { c1[row] = sh[0] + sh[1]; c2[row] = sh[2] + sh[3]; }
}

// ---------------- m97-style MFMA GEMM: C[m,n] = sum_k A[m,k]*B[n,k] ----------------
// BM=BN=128, BK=32, 256 threads (4 waves, 2x2), global_load_lds staging.
// A rows and B rows MUST be padded to the grid coverage (no bounds checks in loop).
// LNF: v = lninv[gn]*(acc - lnm[gn]*lnc1[gm]) + lnc2[gm] (fused LayerNorm-of-B epilogue).
#define BK 32
template<int OUT_BF, int RELU, int LNF>
__launch_bounds__(256)
__global__ void k_gemm128(const unsigned short* __restrict__ A,
                          const unsigned short* __restrict__ B,
                          const float* __restrict__ bias,
                          const float* __restrict__ addb,
                          void* __restrict__ Cout,
                          int K, int ldc,
                          int Mvalid, int Nvalid, int Nstore, int swap,
                          const float* __restrict__ lnm, const float* __restrict__ lninv,
                          const float* __restrict__ lnc1, const float* __restrict__ lnc2) {
  __shared__ unsigned short As[128 * BK];
  __shared__ unsigned short Bs[128 * BK];
  const int tid = threadIdx.x;
  const int w = tid >> 6, lane = tid & 63;
  const int bm = swap ? blockIdx.y : blockIdx.x;
  const int bn = swap ? blockIdx.x : blockIdx.y;
  const int m0 = bm * 128, n0 = bn * 128;
  const int wm = w & 1, wn = w >> 1;
  const int lr = lane & 15, q = lane >> 4;

  const int srow = w * 32 + (lane >> 2);
  const int scol = (lane & 3) * 8;
  const unsigned short* Ag = A + (size_t)(m0 + srow) * K + scol;
  const unsigned short* Bg = B + (size_t)(n0 + srow) * K + scol;
  unsigned short* Asl0 = As + (w * 32) * BK;
  unsigned short* Asl1 = As + (w * 32 + 16) * BK;
  unsigned short* Bsl0 = Bs + (w * 32) * BK;
  unsigned short* Bsl1 = Bs + (w * 32 + 16) * BK;

  f32x4_t acc[4][4];
#pragma unroll
  for (int r = 0; r < 4; ++r)
#pragma unroll
    for (int t = 0; t < 4; ++t) { f32x4_t z = {0.f, 0.f, 0.f, 0.f}; acc[r][t] = z; }

  for (int k0 = 0; k0 < K; k0 += BK) {
    __syncthreads();
    gl_lds16(Ag, Asl0);
    gl_lds16(Ag + 16 * (size_t)K, Asl1);
    gl_lds16(Bg, Bsl0);
    gl_lds16(Bg + 16 * (size_t)K, Bsl1);
    Ag += BK; Bg += BK;
    __syncthreads();
    bf16x8_t af[4], bfv[4];
#pragma unroll
    for (int r = 0; r < 4; ++r)
      af[r] = *(const bf16x8_t*)(As + (wm * 64 + r * 16 + lr) * BK + q * 8);
#pragma unroll
    for (int t = 0; t < 4; ++t)
      bfv[t] = *(const bf16x8_t*)(Bs + (wn * 64 + t * 16 + lr) * BK + q * 8);
#pragma unroll
    for (int r = 0; r < 4; ++r)
#pragma unroll
      for (int t = 0; t < 4; ++t)
        acc[r][t] = __builtin_amdgcn_mfma_f32_16x16x32_bf16(af[r], bfv[t], acc[r][t], 0, 0, 0);
  }

#pragma unroll
  for (int r = 0; r < 4; ++r) {
#pragma unroll
    for (int t = 0; t < 4; ++t) {
#pragma unroll
      for (int e = 0; e < 4; ++e) {
        int gm = m0 + wm * 64 + r * 16 + q * 4 + e;
        int gn = n0 + wn * 64 + t * 16 + lr;
        if (gn < Nstore) {
          float v = 0.f;
          if (gm < Mvalid && gn < Nvalid) {
            v = acc[r][t][e];
            if (LNF) {
              v = lninv[gn] * (v - lnm[gn] * lnc1[gm]) + lnc2[gm];
            } else {
              if (bias) v += bias[gn];
              if (addb) v += addb[(size_t)gm * ldc + gn];
              if (RELU) v = fmaxf(v, 0.f);
            }
          }
          if (OUT_BF) ((unsigned short*)Cout)[(size_t)gm * ldc + gn] = f2bf(v);
          else        ((float*)Cout)[(size_t)gm * ldc + gn] = v;
        }
      }
    }
  }
}

// ---------------- LayerNorm over D=800 (f32 in, bf16 out) — image branch only ----------------
__global__ void k_ln_img(const float* __restrict__ in, unsigned short* __restrict__ out,
                         const float* __restrict__ g, const float* __restrict__ b) {
  const int row = blockIdx.x, t = threadIdx.x;
  float v[4]; float s = 0.f, ss = 0.f; int j = 0;
  for (int idx = t; idx < 800; idx += 256, ++j) {
    float x = in[(size_t)row * 800 + idx];
    v[j] = x; s += x; ss += x * x;
  }
#pragma unroll
  for (int off = 32; off > 0; off >>= 1) {
    s += __shfl_down(s, off);
    ss += __shfl_down(ss, off);
  }
  __shared__ float sh[8];
  int wave = t >> 6, lane = t & 63;
  if (lane == 0) { sh[wave] = s; sh[4 + wave] = ss; }
  __syncthreads();
  if (t == 0) {
    float S = sh[0] + sh[1] + sh[2] + sh[3];
    float SS = sh[4] + sh[5] + sh[6] + sh[7];
    float m = S * (1.0f / 800.0f);
    float var = SS * (1.0f / 800.0f) - m * m;
    sh[0] = m; sh[1] = rsqrtf(fmaxf(var, 0.f) + 1e-5f);
  }
  __syncthreads();
  float m = sh[0], inv = sh[1];
  j = 0;
  for (int idx = t; idx < 800; idx += 256, ++j) {
    float y = (v[j] - m) * inv * g[idx] + b[idx];
    out[(size_t)row * 800 + idx] = f2bf(y);
  }
}

// ---------------- host ----------------
extern "C" void kernel_launch(void* const* d_in, const int* in_sizes, int n_in,
                              void* d_out, int out_size, void* d_ws, size_t ws_size,
                              hipStream_t stream) {
  (void)in_sizes; (void)n_in; (void)out_size; (void)ws_size;
  const float* img  = (const float*)d_in[0];
  const float* nodes= (const float*)d_in[1];
  const int* esrc   = (const int*)d_in[2];
  const int* edst   = (const int*)d_in[3];
  const float* W1l  = (const float*)d_in[4];
  const float* b1   = (const float*)d_in[5];
  const float* W1r  = (const float*)d_in[6];
  const float* W2l  = (const float*)d_in[7];
  const float* b2   = (const float*)d_in[8];
  const float* W2r  = (const float*)d_in[9];
  const float* Wp1  = (const float*)d_in[10];
  const float* bp1  = (const float*)d_in[11];
  const float* Wp2  = (const float*)d_in[12];
  const float* bp2  = (const float*)d_in[13];
  const float* gp   = (const float*)d_in[14];
  const float* bpn  = (const float*)d_in[15];
  const float* Wi1  = (const float*)d_in[16];
  const float* bi1  = (const float*)d_in[17];
  const float* Wi2  = (const float*)d_in[18];
  const float* bi2  = (const float*)d_in[19];
  const float* Wi3  = (const float*)d_in[20];
  const float* bi3  = (const float*)d_in[21];
  const float* gi   = (const float*)d_in[22];
  const float* binp = (const float*)d_in[23];

  char* wsp = (char*)d_ws;
  auto alloc = [&](size_t bytes) -> void* {
    void* p = (void*)wsp; wsp += (bytes + 255) & ~(size_t)255; return p;
  };
  // persistent (live across the pair stage)
  unsigned short* onB    = (unsigned short*)alloc((size_t)768 * 512 * 2);
  unsigned short* Wp1LB  = (unsigned short*)alloc((size_t)1280 * 512 * 2);
  unsigned short* Wp1RB  = (unsigned short*)alloc((size_t)1280 * 512 * 2);
  unsigned short* Wp2B   = (unsigned short*)alloc((size_t)896 * 1216 * 2);
  float* PaB             = (float*)alloc((size_t)256 * 1216 * 4);
  float* PoB             = (float*)alloc((size_t)512 * 1216 * 4);
  unsigned short* imgB   = (unsigned short*)alloc((size_t)256 * 2048 * 2);
  unsigned short* Wi1B   = (unsigned short*)alloc((size_t)768 * 2048 * 2);
  unsigned short* Wi2B   = (unsigned short*)alloc((size_t)1024 * 768 * 2);
  unsigned short* Wi3B   = (unsigned short*)alloc((size_t)896 * 1024 * 2);
  unsigned short* i1B    = (unsigned short*)alloc((size_t)256 * 768 * 2);
  unsigned short* i2B    = (unsigned short*)alloc((size_t)256 * 1024 * 2);
  float* i3F             = (float*)alloc((size_t)256 * 800 * 4);
  unsigned short* iB     = (unsigned short*)alloc((size_t)256 * 800 * 2);
  unsigned short* iG     = (unsigned short*)alloc((size_t)256 * 800 * 2);
  float* c1B             = (float*)alloc(256 * 4);
  float* c2B             = (float*)alloc(256 * 4);
  float* mArr            = (float*)alloc((size_t)100096 * 4);
  float* ivArr           = (float*)alloc((size_t)100096 * 4);
  unsigned short* qB     = (unsigned short*)alloc((size_t)100096 * 800 * 2);

  // node-stage scratch overlays the qB region (dead before first qB write)
  char* swp = (char*)qB;
  auto salloc = [&](size_t bytes) -> void* {
    void* p = (void*)swp; swp += (bytes + 255) & ~(size_t)255; return p;
  };
  float* adjC            = (float*)salloc((size_t)NN * NN * 4);
  float* deg             = (float*)salloc(NN * 4);
  unsigned short* Cn     = (unsigned short*)salloc((size_t)768 * 672 * 2);
  unsigned short* nodesB = (unsigned short*)salloc((size_t)768 * 512 * 2);
  unsigned short* nodesT = (unsigned short*)salloc((size_t)512 * 672 * 2);
  unsigned short* agg1   = (unsigned short*)salloc((size_t)768 * 512 * 2);
  float* tmp1            = (float*)salloc((size_t)768 * 4096 * 4);
  unsigned short* hB     = (unsigned short*)salloc((size_t)768 * 4096 * 2);
  unsigned short* hT     = (unsigned short*)salloc((size_t)4096 * 672 * 2);
  unsigned short* agg2   = (unsigned short*)salloc((size_t)768 * 4096 * 2);
  float* tmp2            = (float*)salloc((size_t)768 * 512 * 4);
  unsigned short* W1lB   = (unsigned short*)salloc((size_t)4096 * 512 * 2);
  unsigned short* W1rB   = (unsigned short*)salloc((size_t)4096 * 512 * 2);
  unsigned short* W2lB   = (unsigned short*)salloc((size_t)512 * 4096 * 2);
  unsigned short* W2rB   = (unsigned short*)salloc((size_t)512 * 4096 * 2);

  // P chunk scratch lives in d_out (102.4 MB; scratch-legal until the final GEMM)
  unsigned short* Pch = (unsigned short*)d_out;  // max 262*128 rows * 1216 * 2 = 81.6 MB

  hipMemsetAsync(adjC, 0, (size_t)NN * NN * 4, stream);
  hipMemsetAsync(deg, 0, NN * 4, stream);

  k_scatter<<<dim3((NE + 255) / 256), 256, 0, stream>>>(esrc, edst, adjC, deg);
  k_adj_norm<<<dim3((768 * 672 + 255) / 256), 256, 0, stream>>>(adjC, deg, Cn);

  // ---- fused converts (one launch) ----
  {
    CvtPack pk; int nj = 0, tot = 0;
    auto addj = [&](const float* s, unsigned short* d, int Mv, int Mp, int Kin, int ldi, int off, int ldo) {
      int ne = Mp * ldo, nb = (ne + 255) / 256;
      pk.d[nj++] = { s, d, Mv, Kin, ldi, off, ldo, ne, nb };
      tot += nb;
    };
    addj(nodes, nodesB, 650, 768, 512, 512, 0, 512);
    addj(W1l, W1lB, 4096, 4096, 512, 512, 0, 512);
    addj(W1r, W1rB, 4096, 4096, 512, 512, 0, 512);
    addj(W2l, W2lB, 512, 512, 4096, 4096, 0, 4096);
    addj(W2r, W2rB, 512, 512, 4096, 4096, 0, 4096);
    addj(Wp1, Wp1LB, 1200, 1280, 512, 1024, 0, 512);
    addj(Wp1, Wp1RB, 1200, 1280, 512, 1024, 512, 512);
    addj(Wp2, Wp2B, 800, 896, 1200, 1200, 0, 1216);
    addj(Wi1, Wi1B, 768, 768, 2048, 2048, 0, 2048);
    addj(Wi2, Wi2B, 1000, 1024, 768, 768, 0, 768);
    addj(Wi3, Wi3B, 800, 896, 1000, 1000, 0, 1024);
    addj(img, imgB, 256, 256, 2048, 2048, 0, 2048);
    k_cvt_all<<<dim3(tot), 256, 0, stream>>>(pk);
  }

  // nodesT[feat][node] from nodesB; out 512 x 672
  k_ttr<<<dim3(512 / 64, (672 + 63) / 64), 256, 0, stream>>>(nodesB, nodesT, 512, 672);

#define NUL nullptr, nullptr, nullptr, nullptr
  // ---- node stage (scratch region) ----
  k_gemm128<1, 0, 0><<<dim3(6, 4), 256, 0, stream>>>(Cn, nodesT, nullptr, nullptr, agg1, 672, 512, 650, 512, 512, 0, NUL);
  k_gemm128<0, 0, 0><<<dim3(6, 32), 256, 0, stream>>>(agg1, W1lB, b1, nullptr, tmp1, 512, 4096, 650, 4096, 4096, 0, NUL);
  k_gemm128<1, 1, 0><<<dim3(6, 32), 256, 0, stream>>>(nodesB, W1rB, nullptr, tmp1, hB, 512, 4096, 650, 4096, 4096, 0, NUL);
  k_ttr<<<dim3(4096 / 64, (672 + 63) / 64), 256, 0, stream>>>(hB, hT, 4096, 672);
  k_gemm128<1, 0, 0><<<dim3(6, 32), 256, 0, stream>>>(Cn, hT, nullptr, nullptr, agg2, 672, 4096, 650, 4096, 4096, 0, NUL);
  k_gemm128<0, 0, 0><<<dim3(6, 4), 256, 0, stream>>>(agg2, W2lB, b2, nullptr, tmp2, 4096, 512, 650, 512, 512, 0, NUL);
  k_gemm128<1, 0, 0><<<dim3(6, 4), 256, 0, stream>>>(hB, W2rB, nullptr, tmp2, onB, 4096, 512, 650, 512, 512, 0, NUL);
  // Pa = attr @ Wp1L.T + bp1 ; Po = obj @ Wp1R.T (f32, ld 1216, cols 1200..1215 zero)
  k_gemm128<0, 0, 0><<<dim3(2, 10), 256, 0, stream>>>(onB, Wp1LB, bp1, nullptr, PaB, 512, 1216, 250, 1200, 1216, 0, NUL);
  k_gemm128<0, 0, 0><<<dim3(4, 10), 256, 0, stream>>>(onB + 250 * 512, Wp1RB, nullptr, nullptr, PoB, 512, 1216, 400, 1200, 1216, 0, NUL);

  // ---- image branch ----
  k_gemm128<1, 1, 0><<<dim3(2, 6), 256, 0, stream>>>(imgB, Wi1B, bi1, nullptr, i1B, 2048, 768, 256, 768, 768, 0, NUL);
  k_gemm128<1, 1, 0><<<dim3(2, 8), 256, 0, stream>>>(i1B, Wi2B, bi2, nullptr, i2B, 768, 1024, 256, 1000, 1024, 0, NUL);
  k_gemm128<0, 0, 0><<<dim3(2, 7), 256, 0, stream>>>(i2B, Wi3B, bi3, nullptr, i3F, 1024, 800, 256, 800, 800, 0, NUL);
  k_ln_img<<<dim3(256), 256, 0, stream>>>(i3F, iB, gi, binp);
  k_prep_i<<<dim3(256), 128, 0, stream>>>(iB, gp, bpn, iG, c1B, c2B);

  // ---- pair stage, chunked: P chunk in d_out -> q chunk GEMM -> stats (L3-hot) ----
  const int CB = 262;                       // m-blocks per chunk
  for (int c = 0; c < 3; ++c) {
    int b0 = c * CB;
    int nb = (782 - b0) < CB ? (782 - b0) : CB;   // 262,262,258
    int r0 = b0 * 128;
    int rows = nb * 128;
    k_pgen<<<dim3((rows * 152 + 255) / 256), 256, 0, stream>>>(PaB, PoB, Pch, r0, rows);
    int mv = (100000 - r0) < rows ? (100000 - r0) : rows;
    k_gemm128<1, 0, 0><<<dim3(7, nb), 256, 0, stream>>>(Pch, Wp2B, bp2, nullptr,
        qB + (size_t)r0 * 800, 1216, 800, mv, 800, 800, 1, NUL);
    k_qstats<<<dim3(rows / 2), 256, 0, stream>>>(qB, mArr, ivArr, r0);
  }

  // ---- out = LN-fused iG @ q.T (f32, 256 x 100000) ----
  k_gemm128<0, 0, 1><<<dim3(2, 782), 256, 0, stream>>>(iG, qB, nullptr, nullptr, (float*)d_out,
      800, 100000, 256, 100000, 100000, 0, mArr, ivArr, c1B, c2B);
#undef NUL
}